// Round 2
// baseline (328.652 us; speedup 1.0000x reference)
//
#include <hip/hip_runtime.h>

// TCN, last-timestep-only receptive-field cone, batch-in-lane layout.
// Intermediates in d_ws laid out as [t][channel][batch(=lane)]:
//   xT : [13][256][64]   t = 1011+r
//   B1 : [11][512][64]   t = 1013+ti  (relu(conv1_0))
//   H0 : [ 5][512][64]   t = 1015+2tj (block-0 output)
//   B2 : [ 3][512][64]   t = 1019+2tk (relu(conv1_1))
//   H1 : [512][64]       t = 1023     (block-1 output)
// Weights are wave-uniform: staged to LDS as [c][oc_l][4] and read as
// broadcast float4 (same-address ds_read_b128 = conflict-free).
// Each conv block: 256 thr = 4 waves = 2 ocs x 2 c-halves, LDS split-K reduce.

#define T_LEN 1024
#define C_INN 256
#define HID 512
#define OUTD 36
#define NB 64

// ---- transpose x window -> xT[r][c][b] ----------------------------------
__global__ __launch_bounds__(256) void k_tr(const float* __restrict__ x,
                                            float* __restrict__ xT) {
    const int r = blockIdx.x, cq = blockIdx.y, tid = threadIdx.x;
    __shared__ float S[64][65];
    for (int it = 0; it < 16; ++it) {
        int i = tid + 256 * it;
        int b = i >> 6, c = i & 63;
        S[b][c] = x[(b * T_LEN + 1011 + r) * C_INN + cq * 64 + c];
    }
    __syncthreads();
    for (int it = 0; it < 16; ++it) {
        int i = tid + 256 * it;
        int c = i >> 6, b = i & 63;
        xT[(r * C_INN + cq * 64 + c) * 64 + b] = S[b][c];
    }
}

// ---- L0: B1 = relu(conv1_0(x)+b), dil=1, 11 outputs ---------------------
__global__ __launch_bounds__(256) void k_l0(const float* __restrict__ xT,
                                            const float* __restrict__ w,
                                            const float* __restrict__ bias,
                                            float* __restrict__ B1) {
    const int ocp = blockIdx.x, tid = threadIdx.x;
    const int lane = tid & 63, wv = tid >> 6;
    const int oc_l = wv & 1, ch = wv >> 1;
    const int oc = ocp * 2 + oc_l;
    __shared__ float W4[C_INN][2][4];
    __shared__ float R[2][11][64];
    for (int idx = tid; idx < 2 * C_INN * 3; idx += 256) {
        int o = idx / 768, rem = idx % 768;
        int c = rem / 3, k = rem % 3;
        W4[c][o][k] = w[ocp * 2 * 768 + idx];
    }
    __syncthreads();
    float binit = (ch == 0) ? bias[oc] : 0.f;
    float acc[11];
#pragma unroll
    for (int t = 0; t < 11; ++t) acc[t] = binit;
    for (int cl = 0; cl < 128; ++cl) {
        int c = ch * 128 + cl;
        float4 wq = *(const float4*)&W4[c][oc_l][0];
        float xa[13];
#pragma unroll
        for (int r = 0; r < 13; ++r) xa[r] = xT[(r * C_INN + c) * 64 + lane];
#pragma unroll
        for (int t = 0; t < 11; ++t)
            acc[t] += wq.x * xa[t] + wq.y * xa[t + 1] + wq.z * xa[t + 2];
    }
    if (ch == 1) {
#pragma unroll
        for (int t = 0; t < 11; ++t) R[oc_l][t][lane] = acc[t];
    }
    __syncthreads();
    if (ch == 0) {
#pragma unroll
        for (int t = 0; t < 11; ++t) {
            float v = acc[t] + R[oc_l][t][lane];
            B1[(t * HID + oc) * 64 + lane] = fmaxf(v, 0.f);
        }
    }
}

// ---- L1: H0 = relu(relu(conv2_0(B1)+b2) + down(x)+bd), 5 outputs --------
__global__ __launch_bounds__(256) void k_l1(const float* __restrict__ xT,
                                            const float* __restrict__ B1,
                                            const float* __restrict__ w2,
                                            const float* __restrict__ b2,
                                            const float* __restrict__ wd,
                                            const float* __restrict__ bd,
                                            float* __restrict__ H0) {
    const int ocp = blockIdx.x, tid = threadIdx.x;
    const int lane = tid & 63, wv = tid >> 6;
    const int oc_l = wv & 1, ch = wv >> 1;
    const int oc = ocp * 2 + oc_l;
    __shared__ float W4[HID][2][4];   // 16 KB
    __shared__ float Wd[2][C_INN];    // 2 KB
    __shared__ float R[2][10][64];    // 5 KB
    for (int idx = tid; idx < 2 * HID * 3; idx += 256) {
        int o = idx / 1536, rem = idx % 1536;
        int c = rem / 3, k = rem % 3;
        W4[c][o][k] = w2[ocp * 2 * 1536 + idx];
    }
    for (int idx = tid; idx < 2 * C_INN; idx += 256) {
        int o = idx >> 8, c = idx & 255;
        Wd[o][c] = wd[(ocp * 2 + o) * C_INN + c];
    }
    __syncthreads();
    float accC[5], accR[5];
    float bC = (ch == 0) ? b2[oc] : 0.f;
    float bR = (ch == 0) ? bd[oc] : 0.f;
#pragma unroll
    for (int t = 0; t < 5; ++t) { accC[t] = bC; accR[t] = bR; }
    for (int cl = 0; cl < 256; ++cl) {
        int c = ch * 256 + cl;
        float4 wq = *(const float4*)&W4[c][oc_l][0];
        float av[11];
#pragma unroll
        for (int r = 0; r < 11; ++r) av[r] = B1[(r * HID + c) * 64 + lane];
#pragma unroll
        for (int t = 0; t < 5; ++t)
            accC[t] += wq.x * av[2 * t] + wq.y * av[2 * t + 1] + wq.z * av[2 * t + 2];
    }
    for (int cl = 0; cl < 128; ++cl) {
        int c = ch * 128 + cl;
        float wdv = Wd[oc_l][c];
#pragma unroll
        for (int t = 0; t < 5; ++t)
            accR[t] += wdv * xT[((4 + 2 * t) * C_INN + c) * 64 + lane];
    }
    if (ch == 1) {
#pragma unroll
        for (int t = 0; t < 5; ++t) {
            R[oc_l][t][lane] = accC[t];
            R[oc_l][5 + t][lane] = accR[t];
        }
    }
    __syncthreads();
    if (ch == 0) {
#pragma unroll
        for (int t = 0; t < 5; ++t) {
            float vc = accC[t] + R[oc_l][t][lane];
            float vr = accR[t] + R[oc_l][5 + t][lane];
            H0[(t * HID + oc) * 64 + lane] = fmaxf(fmaxf(vc, 0.f) + vr, 0.f);
        }
    }
}

// ---- L2: B2 = relu(conv1_1(H0)+b), dil=2, 3 outputs ---------------------
__global__ __launch_bounds__(256) void k_l2(const float* __restrict__ H0,
                                            const float* __restrict__ w,
                                            const float* __restrict__ bias,
                                            float* __restrict__ B2) {
    const int ocp = blockIdx.x, tid = threadIdx.x;
    const int lane = tid & 63, wv = tid >> 6;
    const int oc_l = wv & 1, ch = wv >> 1;
    const int oc = ocp * 2 + oc_l;
    __shared__ float W4[HID][2][4];
    __shared__ float R[2][3][64];
    for (int idx = tid; idx < 2 * HID * 3; idx += 256) {
        int o = idx / 1536, rem = idx % 1536;
        int c = rem / 3, k = rem % 3;
        W4[c][o][k] = w[ocp * 2 * 1536 + idx];
    }
    __syncthreads();
    float binit = (ch == 0) ? bias[oc] : 0.f;
    float acc[3] = {binit, binit, binit};
    for (int cl = 0; cl < 256; ++cl) {
        int c = ch * 256 + cl;
        float4 wq = *(const float4*)&W4[c][oc_l][0];
        float av[5];
#pragma unroll
        for (int r = 0; r < 5; ++r) av[r] = H0[(r * HID + c) * 64 + lane];
#pragma unroll
        for (int t = 0; t < 3; ++t)
            acc[t] += wq.x * av[t] + wq.y * av[t + 1] + wq.z * av[t + 2];
    }
    if (ch == 1) {
#pragma unroll
        for (int t = 0; t < 3; ++t) R[oc_l][t][lane] = acc[t];
    }
    __syncthreads();
    if (ch == 0) {
#pragma unroll
        for (int t = 0; t < 3; ++t) {
            float v = acc[t] + R[oc_l][t][lane];
            B2[(t * HID + oc) * 64 + lane] = fmaxf(v, 0.f);
        }
    }
}

// ---- L3: H1 = relu(relu(conv2_1(B2)+b) + H0[t=1023]) --------------------
__global__ __launch_bounds__(256) void k_l3(const float* __restrict__ B2,
                                            const float* __restrict__ H0,
                                            const float* __restrict__ w,
                                            const float* __restrict__ bias,
                                            float* __restrict__ H1) {
    const int ocp = blockIdx.x, tid = threadIdx.x;
    const int lane = tid & 63, wv = tid >> 6;
    const int oc_l = wv & 1, ch = wv >> 1;
    const int oc = ocp * 2 + oc_l;
    __shared__ float W4[HID][2][4];
    __shared__ float R[2][64];
    for (int idx = tid; idx < 2 * HID * 3; idx += 256) {
        int o = idx / 1536, rem = idx % 1536;
        int c = rem / 3, k = rem % 3;
        W4[c][o][k] = w[ocp * 2 * 1536 + idx];
    }
    __syncthreads();
    float acc = (ch == 0) ? bias[oc] : 0.f;
    for (int cl = 0; cl < 256; ++cl) {
        int c = ch * 256 + cl;
        float4 wq = *(const float4*)&W4[c][oc_l][0];
        float a0 = B2[(0 * HID + c) * 64 + lane];
        float a1 = B2[(1 * HID + c) * 64 + lane];
        float a2 = B2[(2 * HID + c) * 64 + lane];
        acc += wq.x * a0 + wq.y * a1 + wq.z * a2;
    }
    if (ch == 1) R[oc_l][lane] = acc;
    __syncthreads();
    if (ch == 0) {
        float v = acc + R[oc_l][lane];
        float res = H0[(4 * HID + oc) * 64 + lane];
        H1[oc * 64 + lane] = fmaxf(fmaxf(v, 0.f) + res, 0.f);
    }
}

// ---- fc: out[b][j] = fc_w[j] . H1[:,b] + fc_b[j] ------------------------
__global__ __launch_bounds__(64) void k_fc(const float* __restrict__ H1,
                                           const float* __restrict__ fcw,
                                           const float* __restrict__ fcb,
                                           float* __restrict__ out) {
    const int j = blockIdx.x, lane = threadIdx.x;
    float acc = fcb[j];
#pragma unroll 8
    for (int o = 0; o < HID; ++o)
        acc += fcw[j * HID + o] * H1[o * 64 + lane];
    out[lane * OUTD + j] = acc;
}

extern "C" void kernel_launch(void* const* d_in, const int* in_sizes, int n_in,
                              void* d_out, int out_size, void* d_ws, size_t ws_size,
                              hipStream_t stream) {
    const float* x    = (const float*)d_in[0];
    const float* w1_0 = (const float*)d_in[4];
    const float* b1_0 = (const float*)d_in[5];
    const float* w2_0 = (const float*)d_in[6];
    const float* b2_0 = (const float*)d_in[7];
    const float* wd0  = (const float*)d_in[8];
    const float* bd0  = (const float*)d_in[9];
    const float* w1_1 = (const float*)d_in[10];
    const float* b1_1 = (const float*)d_in[11];
    const float* w2_1 = (const float*)d_in[12];
    const float* b2_1 = (const float*)d_in[13];
    const float* fcw  = (const float*)d_in[14];
    const float* fcb  = (const float*)d_in[15];
    float* out = (float*)d_out;

    float* xT = (float*)d_ws;                 // 13*256*64
    float* B1 = xT + 13 * C_INN * 64;         // 11*512*64
    float* H0 = B1 + 11 * HID * 64;           // 5*512*64
    float* B2 = H0 + 5 * HID * 64;            // 3*512*64
    float* H1 = B2 + 3 * HID * 64;            // 512*64

    k_tr<<<dim3(13, 4), 256, 0, stream>>>(x, xT);
    k_l0<<<256, 256, 0, stream>>>(xT, w1_0, b1_0, B1);
    k_l1<<<256, 256, 0, stream>>>(xT, B1, w2_0, b2_0, wd0, bd0, H0);
    k_l2<<<256, 256, 0, stream>>>(H0, w1_1, b1_1, B2);
    k_l3<<<256, 256, 0, stream>>>(B2, H0, w2_1, b2_1, H1);
    k_fc<<<OUTD, 64, 0, stream>>>(H1, fcw, fcb, out);
}

// Round 3
// 146.519 us; speedup vs baseline: 2.2431x; 2.2431x over previous
//
#include <hip/hip_runtime.h>

// TCN, last-timestep receptive-field cone, as 5 split-K tiled GEMMs + fc.
// All activations in d_ws, layout [channel][t'][64 b] (fp32).
// Partial sums per layer: P[ks][512 oc][T_OUT][64 b]; the consumer's staging
// fuses the ks-reduction + bias + relu while transposing into LDS [c][b][t'].
//
// t mapping (all relative windows):
//   xT: t = 1011+r, r in [0,13)
//   L0 (conv1_0, dil1): B1 t=1013+ti, ti in [0,11): t_in = ti + kk
//   L1 (conv2_0, dil1): H0 t=1015+2tj, tj in [0,5): t_in = 2tj + kk (in B1 coords)
//   down (1-tap):                         t_in = 2tj + 4   (in xT coords)
//   L2 (conv1_1, dil2): B2 t=1019+2tk, tk in [0,3): t_in = tk + kk (in H0 coords)
//   L3 (conv2_1, dil2): H1 t=1023:                  t_in = kk      (in B2 coords)

#define HIDC 512
#define OUTD 36

// ---- transpose x window -> xT[c][r][b], r=0..12 (t=1011+r) --------------
__global__ __launch_bounds__(256) void k_tr(const float* __restrict__ x,
                                            float* __restrict__ xT) {
    const int r = blockIdx.x, cq = blockIdx.y, tid = threadIdx.x;
    __shared__ float S[64][65];
    for (int it = 0; it < 16; ++it) {
        int i = tid + 256 * it;
        int b = i >> 6, c = i & 63;
        S[b][c] = x[(b * 1024 + 1011 + r) * 256 + cq * 64 + c];
    }
    __syncthreads();
    for (int it = 0; it < 16; ++it) {
        int i = tid + 256 * it;
        int c = i >> 6, b = i & 63;
        xT[((cq * 64 + c) * 13 + r) * 64 + b] = S[b][c];
    }
}

// ---- generic split-K conv-GEMM ------------------------------------------
// src1: if P1N==0: raw act [CIN][TIN][64]; else partials [P1N][CIN][TIN][64],
//       staged value = relu(sum_p src1 + bias1[c]); if P2N>0 additionally
//       value = relu(value + sum_p src2 + bias2[c]).
// w: [512 oc][CIN][TAPS].  Pout: [gridDim.y][512][TOUT][64] partials (no bias).
// grid: (512/OCT, KS); each block loops NCH chunks of CCH channels.
template <int CIN, int TIN, int TOUT, int S, int D, int OFF, int TAPS,
          int OCT, int CCH, int NCH, int P1N, int P2N>
__global__ __launch_bounds__(256) void k_conv(
    const float* __restrict__ src1, const float* __restrict__ bias1,
    const float* __restrict__ src2, const float* __restrict__ bias2,
    const float* __restrict__ w, float* __restrict__ Pout) {
    const int tid = threadIdx.x, lane = tid & 63, wv = tid >> 6;
    const int ocp = blockIdx.x, ks = blockIdx.y;
    const int oc0 = ocp * OCT;
    constexpr int OCR = OCT / 4;
    constexpr int TINP = TIN;  // odd (13/11/5/3) -> bank-conflict-free
    __shared__ float Als[CCH * TAPS * OCT];
    __shared__ float Bls[CCH * 64 * TINP];
    float acc[OCR][TOUT];
#pragma unroll
    for (int i = 0; i < OCR; ++i)
#pragma unroll
        for (int t = 0; t < TOUT; ++t) acc[i][t] = 0.f;

    for (int ch = 0; ch < NCH; ++ch) {
        const int c0 = (ks * NCH + ch) * CCH;
        if (ch) __syncthreads();
        // stage A (weights) [c][kk][oc]
        for (int idx = tid; idx < OCT * CCH * TAPS; idx += 256) {
            int i = idx / (CCH * TAPS), r = idx % (CCH * TAPS);
            int c = r / TAPS, kk = r % TAPS;
            Als[(c * TAPS + kk) * OCT + i] =
                w[(size_t)(oc0 + i) * (CIN * TAPS) + (c0 + c) * TAPS + kk];
        }
        // stage B (activations) -> Bls[c][b][t'], fusing ks-reduce+bias+relu
        for (int idx = tid; idx < CCH * TIN * 16; idx += 256) {
            int c = idx / (TIN * 16), r = idx % (TIN * 16);
            int t = r / 16, b4 = (r % 16) * 4;
            float4 v;
            if constexpr (P1N == 0) {
                v = *(const float4*)(src1 + ((size_t)(c0 + c) * TIN + t) * 64 + b4);
            } else {
                float4 s = {0.f, 0.f, 0.f, 0.f};
#pragma unroll
                for (int p = 0; p < P1N; ++p) {
                    float4 u = *(const float4*)(src1 +
                        (((size_t)p * CIN + c0 + c) * TIN + t) * 64 + b4);
                    s.x += u.x; s.y += u.y; s.z += u.z; s.w += u.w;
                }
                float bb = bias1[c0 + c];
                s.x = fmaxf(s.x + bb, 0.f); s.y = fmaxf(s.y + bb, 0.f);
                s.z = fmaxf(s.z + bb, 0.f); s.w = fmaxf(s.w + bb, 0.f);
                if constexpr (P2N > 0) {
                    float4 s2 = {0.f, 0.f, 0.f, 0.f};
#pragma unroll
                    for (int p = 0; p < P2N; ++p) {
                        float4 u = *(const float4*)(src2 +
                            (((size_t)p * CIN + c0 + c) * TIN + t) * 64 + b4);
                        s2.x += u.x; s2.y += u.y; s2.z += u.z; s2.w += u.w;
                    }
                    float b2v = bias2[c0 + c];
                    s.x = fmaxf(s.x + s2.x + b2v, 0.f);
                    s.y = fmaxf(s.y + s2.y + b2v, 0.f);
                    s.z = fmaxf(s.z + s2.z + b2v, 0.f);
                    s.w = fmaxf(s.w + s2.w + b2v, 0.f);
                }
                v = s;
            }
            Bls[(c * 64 + b4 + 0) * TINP + t] = v.x;
            Bls[(c * 64 + b4 + 1) * TINP + t] = v.y;
            Bls[(c * 64 + b4 + 2) * TINP + t] = v.z;
            Bls[(c * 64 + b4 + 3) * TINP + t] = v.w;
        }
        __syncthreads();
        // compute
        for (int c = 0; c < CCH; ++c) {
            float bv[TIN];
#pragma unroll
            for (int u = 0; u < TIN; ++u) bv[u] = Bls[(c * 64 + lane) * TINP + u];
            float av[TAPS][OCR];
#pragma unroll
            for (int kk = 0; kk < TAPS; ++kk)
#pragma unroll
                for (int i = 0; i < OCR; ++i)
                    av[kk][i] = Als[(c * TAPS + kk) * OCT + wv * OCR + i];
#pragma unroll
            for (int i = 0; i < OCR; ++i)
#pragma unroll
                for (int t = 0; t < TOUT; ++t)
#pragma unroll
                    for (int kk = 0; kk < TAPS; ++kk)
                        acc[i][t] += av[kk][i] * bv[S * t + D * kk + OFF];
        }
    }
#pragma unroll
    for (int i = 0; i < OCR; ++i)
#pragma unroll
        for (int t = 0; t < TOUT; ++t)
            Pout[(((size_t)blockIdx.y * HIDC + oc0 + wv * OCR + i) * TOUT + t) * 64 +
                 lane] = acc[i][t];
}

// ---- final: H1 = relu(relu(sum P3 + b2_1) + H0[t=4]); out = fc ----------
__global__ __launch_bounds__(512) void k_fc(
    const float* __restrict__ P3, const float* __restrict__ P1,
    const float* __restrict__ PD, const float* __restrict__ b2_1,
    const float* __restrict__ b2_0, const float* __restrict__ bd0,
    const float* __restrict__ fcw, const float* __restrict__ fcb,
    float* __restrict__ out) {
    const int b = blockIdx.x, tid = threadIdx.x;
    __shared__ float H1s[HIDC];
    __shared__ float fcP[OUTD][8];
    {
        const int oc = tid;
        float s3 = 0.f, s1 = 0.f, sd = 0.f;
#pragma unroll
        for (int p = 0; p < 16; ++p) s3 += P3[((size_t)p * HIDC + oc) * 64 + b];
#pragma unroll
        for (int p = 0; p < 16; ++p)
            s1 += P1[(((size_t)p * HIDC + oc) * 5 + 4) * 64 + b];
#pragma unroll
        for (int p = 0; p < 8; ++p)
            sd += PD[(((size_t)p * HIDC + oc) * 5 + 4) * 64 + b];
        float h0 = fmaxf(fmaxf(s1 + b2_0[oc], 0.f) + sd + bd0[oc], 0.f);
        H1s[oc] = fmaxf(fmaxf(s3 + b2_1[oc], 0.f) + h0, 0.f);
    }
    __syncthreads();
    if (tid < OUTD * 8) {
        int j = tid >> 3, part = tid & 7;
        float s = 0.f;
        for (int o = part; o < HIDC; o += 8) s += fcw[j * HIDC + o] * H1s[o];
        fcP[j][part] = s;
    }
    __syncthreads();
    if (tid < OUTD) {
        float s = fcb[tid];
#pragma unroll
        for (int r = 0; r < 8; ++r) s += fcP[tid][r];
        out[b * OUTD + tid] = s;
    }
}

extern "C" void kernel_launch(void* const* d_in, const int* in_sizes, int n_in,
                              void* d_out, int out_size, void* d_ws, size_t ws_size,
                              hipStream_t stream) {
    const float* x    = (const float*)d_in[0];
    const float* w1_0 = (const float*)d_in[4];
    const float* b1_0 = (const float*)d_in[5];
    const float* w2_0 = (const float*)d_in[6];
    const float* b2_0 = (const float*)d_in[7];
    const float* wd0  = (const float*)d_in[8];
    const float* bd0  = (const float*)d_in[9];
    const float* w1_1 = (const float*)d_in[10];
    const float* b1_1 = (const float*)d_in[11];
    const float* w2_1 = (const float*)d_in[12];
    const float* b2_1 = (const float*)d_in[13];
    const float* fcw  = (const float*)d_in[14];
    const float* fcb  = (const float*)d_in[15];
    float* out = (float*)d_out;

    float* xT = (float*)d_ws;                   // 256*13*64      = 212992
    float* P0 = xT + 256 * 13 * 64;             // 8*512*11*64    = 2883584
    float* P1 = P0 + 8 * 512 * 11 * 64;         // 16*512*5*64    = 2621440
    float* PD = P1 + 16 * 512 * 5 * 64;         // 8*512*5*64     = 1310720
    float* P2 = PD + 8 * 512 * 5 * 64;          // 16*512*3*64    = 1572864
    float* P3 = P2 + 16 * 512 * 3 * 64;         // 16*512*1*64    = 524288

    k_tr<<<dim3(13, 4), 256, 0, stream>>>(x, xT);
    // L0: CIN=256,TIN=13,TOUT=11,S=1,D=1,OFF=0,TAPS=3, OCT=16,CCH=16,NCH=2, P=0
    k_conv<256, 13, 11, 1, 1, 0, 3, 16, 16, 2, 0, 0>
        <<<dim3(32, 8), 256, 0, stream>>>(xT, nullptr, nullptr, nullptr, w1_0, P0);
    // down: CIN=256,TIN=13,TOUT=5,S=2,D=0,OFF=4,TAPS=1, OCT=32,CCH=16,NCH=2
    k_conv<256, 13, 5, 2, 0, 4, 1, 32, 16, 2, 0, 0>
        <<<dim3(16, 8), 256, 0, stream>>>(xT, nullptr, nullptr, nullptr, wd0, PD);
    // L1: CIN=512,TIN=11,TOUT=5,S=2,D=1,OFF=0,TAPS=3, OCT=32,CCH=16,NCH=2, P1N=8
    k_conv<512, 11, 5, 2, 1, 0, 3, 32, 16, 2, 8, 0>
        <<<dim3(16, 16), 256, 0, stream>>>(P0, b1_0, nullptr, nullptr, w2_0, P1);
    // L2: CIN=512,TIN=5,TOUT=3,S=1,D=1,OFF=0,TAPS=3, OCT=32,CCH=32,NCH=1, 16+8
    k_conv<512, 5, 3, 1, 1, 0, 3, 32, 32, 1, 16, 8>
        <<<dim3(16, 16), 256, 0, stream>>>(P1, b2_0, PD, bd0, w1_1, P2);
    // L3: CIN=512,TIN=3,TOUT=1,S=1,D=1,OFF=0,TAPS=3, OCT=32,CCH=32,NCH=1, 16
    k_conv<512, 3, 1, 1, 1, 0, 3, 32, 32, 1, 16, 0>
        <<<dim3(16, 16), 256, 0, stream>>>(P2, b1_1, nullptr, nullptr, w2_1, P3);
    k_fc<<<64, 512, 0, stream>>>(P3, P1, PD, b2_1, b2_0, bd0, fcw, fcb, out);
}

// Round 4
// 124.959 us; speedup vs baseline: 2.6301x; 1.1725x over previous
//
#include <hip/hip_runtime.h>

// TCN, last-timestep receptive-field cone. Pipeline:
//   L0 conv (x->P0 partials)      down conv (x->PD partials)
//   R0: B1 = relu(sum P0 + b1_0)                    [512][64][12]
//   L1 conv (B1->P1)
//   R1: H0 = relu(relu(sum P1 + b2_0) + sum PD + bd0)  [512][64][12]
//   L2 conv (H0->P2)
//   R2: B2 = relu(sum P2 + b1_1)                    [512][64][4]
//   L3 conv (B2->P3)
//   R3: H1 = relu(relu(sum P3 + b2_1) + H0[t=1023]) [512][64]
//   fc
// Activations stored [c][b][TP] so conv B-staging is a contiguous copy.
// Conv partials stored [ks][oc][t][b] (lane-coalesced writes); reduces do
// the t<->b transpose through a tiny LDS tile.
// t-index maps (u = staged time index):
//   L0: u=ti+kk (x t=1011+u)   down: u=tj (x t=1015+2u, staged strided)
//   L1: u=2tj+kk (B1)          L2: u=tk+kk (H0)        L3: u=kk (B2)

#define OUTD 36

// ---- generic split-K conv-GEMM: Pout[ks][512][TOUT][64] (no bias) -------
template <int CIN, int TS_N, int TP, int TOUT, int S, int D, int OFF, int TAPS,
          int OCT, int CCH, int NCH, bool SRC_X, int TS_BASE, int TS_STEP>
__global__ __launch_bounds__(256) void k_conv(const float* __restrict__ src,
                                              const float* __restrict__ w,
                                              float* __restrict__ Pout) {
    const int tid = threadIdx.x, lane = tid & 63, wv = tid >> 6;
    const int oc0 = blockIdx.x * OCT;
    constexpr int OCR = OCT / 4;
    __shared__ float Als[CCH * TAPS * OCT];
    __shared__ float Bls[CCH * 64 * TP];
    float acc[OCR][TOUT];
#pragma unroll
    for (int i = 0; i < OCR; ++i)
#pragma unroll
        for (int t = 0; t < TOUT; ++t) acc[i][t] = 0.f;

    for (int ch = 0; ch < NCH; ++ch) {
        const int c0 = (blockIdx.y * NCH + ch) * CCH;
        if (ch) __syncthreads();
        // stage weights: Als[c][kk][oc]
        for (int idx = tid; idx < OCT * CCH * TAPS; idx += 256) {
            int i = idx / (CCH * TAPS), r = idx % (CCH * TAPS);
            int c = r / TAPS, kk = r % TAPS;
            Als[(c * TAPS + kk) * OCT + i] =
                w[(size_t)(oc0 + i) * (CIN * TAPS) + (c0 + c) * TAPS + kk];
        }
        // stage activations: Bls[c][b][u]
        if constexpr (SRC_X) {
            for (int idx = tid; idx < CCH * TS_N * 64; idx += 256) {
                int c = idx % CCH, rb = idx / CCH;
                int b = rb & 63, u = rb >> 6;
                Bls[(c * 64 + b) * TP + u] =
                    src[((size_t)b * 1024 + 1011 + TS_BASE + TS_STEP * u) * 256 +
                        c0 + c];
            }
        } else {
            const float4* gp = (const float4*)(src + (size_t)c0 * 64 * TP);
            float4* lp = (float4*)Bls;
            for (int idx = tid; idx < CCH * 64 * TP / 4; idx += 256)
                lp[idx] = gp[idx];
        }
        __syncthreads();
        constexpr int NLOAD = (TP % 4 == 0) ? TP : TS_N;
        for (int c = 0; c < CCH; ++c) {
            float bv[NLOAD];
            if constexpr (TP % 4 == 0) {
#pragma unroll
                for (int q = 0; q < TP / 4; ++q)
                    *(float4*)&bv[4 * q] =
                        *(const float4*)&Bls[(c * 64 + lane) * TP + 4 * q];
            } else {
#pragma unroll
                for (int u = 0; u < TS_N; ++u)
                    bv[u] = Bls[(c * 64 + lane) * TP + u];
            }
            float av[TAPS][OCR];
#pragma unroll
            for (int kk = 0; kk < TAPS; ++kk)
#pragma unroll
                for (int j = 0; j < OCR; j += 4)
                    *(float4*)&av[kk][j] =
                        *(const float4*)&Als[(c * TAPS + kk) * OCT + wv * OCR + j];
#pragma unroll
            for (int i = 0; i < OCR; ++i)
#pragma unroll
                for (int t = 0; t < TOUT; ++t)
#pragma unroll
                    for (int kk = 0; kk < TAPS; ++kk)
                        acc[i][t] += av[kk][i] * bv[S * t + D * kk + OFF];
        }
    }
#pragma unroll
    for (int i = 0; i < OCR; ++i)
#pragma unroll
        for (int t = 0; t < TOUT; ++t)
            Pout[(((size_t)blockIdx.y * 512 + oc0 + wv * OCR + i) * TOUT + t) * 64 +
                 lane] = acc[i][t];
}

// ---- reduce: out[oc][b][TPo] = relu-chain over partials -----------------
// s = relu(sum_KS1 P1 + bias1); if KS2: s = relu(s + sum_KS2 P2 + bias2);
// if RES: s = relu(s + res[oc][b][t=4 of 12])   (TPo==1 path, direct write)
template <int KS1, int T, int TPo, int KS2, bool RES>
__global__ __launch_bounds__(256) void k_red(const float* __restrict__ P1,
                                             const float* __restrict__ bias1,
                                             const float* __restrict__ P2,
                                             const float* __restrict__ bias2,
                                             const float* __restrict__ res,
                                             float* __restrict__ outp) {
    const int oc = blockIdx.x, tid = threadIdx.x;
    __shared__ float Sm[64 * TPo];
    if constexpr (TPo > 1) {
        for (int i = tid; i < 64 * TPo; i += 256) Sm[i] = 0.f;
        __syncthreads();
    }
    if (tid < T * 16) {
        const int t = tid / 16, b4 = (tid % 16) * 4;
        float4 s = make_float4(0.f, 0.f, 0.f, 0.f);
#pragma unroll
        for (int p = 0; p < KS1; ++p) {
            float4 u =
                *(const float4*)(P1 + (((size_t)p * 512 + oc) * T + t) * 64 + b4);
            s.x += u.x; s.y += u.y; s.z += u.z; s.w += u.w;
        }
        const float b1 = bias1[oc];
        s.x = fmaxf(s.x + b1, 0.f); s.y = fmaxf(s.y + b1, 0.f);
        s.z = fmaxf(s.z + b1, 0.f); s.w = fmaxf(s.w + b1, 0.f);
        if constexpr (KS2 > 0) {
            float4 s2 = make_float4(0.f, 0.f, 0.f, 0.f);
#pragma unroll
            for (int p = 0; p < KS2; ++p) {
                float4 u =
                    *(const float4*)(P2 + (((size_t)p * 512 + oc) * T + t) * 64 + b4);
                s2.x += u.x; s2.y += u.y; s2.z += u.z; s2.w += u.w;
            }
            const float b2v = bias2[oc];
            s.x = fmaxf(s.x + s2.x + b2v, 0.f);
            s.y = fmaxf(s.y + s2.y + b2v, 0.f);
            s.z = fmaxf(s.z + s2.z + b2v, 0.f);
            s.w = fmaxf(s.w + s2.w + b2v, 0.f);
        }
        if constexpr (RES) {
            s.x = fmaxf(s.x + res[((size_t)oc * 64 + b4 + 0) * 12 + 4], 0.f);
            s.y = fmaxf(s.y + res[((size_t)oc * 64 + b4 + 1) * 12 + 4], 0.f);
            s.z = fmaxf(s.z + res[((size_t)oc * 64 + b4 + 2) * 12 + 4], 0.f);
            s.w = fmaxf(s.w + res[((size_t)oc * 64 + b4 + 3) * 12 + 4], 0.f);
        }
        if constexpr (TPo == 1) {
            *(float4*)(outp + (size_t)oc * 64 + b4) = s;
        } else {
            Sm[(b4 + 0) * TPo + t] = s.x;
            Sm[(b4 + 1) * TPo + t] = s.y;
            Sm[(b4 + 2) * TPo + t] = s.z;
            Sm[(b4 + 3) * TPo + t] = s.w;
        }
    }
    if constexpr (TPo > 1) {
        __syncthreads();
        float4* op = (float4*)(outp + (size_t)oc * 64 * TPo);
        for (int i = tid; i < 64 * TPo / 4; i += 256)
            op[i] = *(const float4*)&Sm[4 * i];
    }
}

// ---- fc: out[b][j] = fc_w[j] . H1[:,b] + fc_b[j] ------------------------
__global__ __launch_bounds__(64) void k_fc(const float* __restrict__ H1,
                                           const float* __restrict__ fcw,
                                           const float* __restrict__ fcb,
                                           float* __restrict__ out) {
    const int j = blockIdx.x, lane = threadIdx.x;
    float acc = fcb[j];
#pragma unroll 8
    for (int o = 0; o < 512; ++o) acc += fcw[j * 512 + o] * H1[o * 64 + lane];
    out[lane * OUTD + j] = acc;
}

extern "C" void kernel_launch(void* const* d_in, const int* in_sizes, int n_in,
                              void* d_out, int out_size, void* d_ws, size_t ws_size,
                              hipStream_t stream) {
    const float* x    = (const float*)d_in[0];
    const float* w1_0 = (const float*)d_in[4];
    const float* b1_0 = (const float*)d_in[5];
    const float* w2_0 = (const float*)d_in[6];
    const float* b2_0 = (const float*)d_in[7];
    const float* wd0  = (const float*)d_in[8];
    const float* bd0  = (const float*)d_in[9];
    const float* w1_1 = (const float*)d_in[10];
    const float* b1_1 = (const float*)d_in[11];
    const float* w2_1 = (const float*)d_in[12];
    const float* b2_1 = (const float*)d_in[13];
    const float* fcw  = (const float*)d_in[14];
    const float* fcb  = (const float*)d_in[15];
    float* out = (float*)d_out;

    float* P0  = (float*)d_ws;                 // 8*512*11*64
    float* B1  = P0 + 8 * 512 * 11 * 64;       // 512*64*12
    float* P1  = B1 + 512 * 64 * 12;           // 16*512*5*64
    float* PD  = P1 + 16 * 512 * 5 * 64;       // 8*512*5*64
    float* H0  = PD + 8 * 512 * 5 * 64;        // 512*64*12
    float* P2  = H0 + 512 * 64 * 12;           // 16*512*3*64
    float* B2  = P2 + 16 * 512 * 3 * 64;       // 512*64*4
    float* P3  = B2 + 512 * 64 * 4;            // 8*512*1*64
    float* H1g = P3 + 8 * 512 * 64;            // 512*64

    // L0: x -> P0   (grid 32 ocp x 8 ks)
    k_conv<256, 13, 13, 11, 1, 1, 0, 3, 16, 16, 2, true, 0, 1>
        <<<dim3(32, 8), 256, 0, stream>>>(x, w1_0, P0);
    // down: x -> PD (grid 16 x 8); staged t = 1015+2u
    k_conv<256, 5, 5, 5, 1, 0, 0, 1, 32, 16, 2, true, 4, 2>
        <<<dim3(16, 8), 256, 0, stream>>>(x, wd0, PD);
    // R0: B1 = relu(sum P0 + b1_0)
    k_red<8, 11, 12, 0, false><<<512, 256, 0, stream>>>(P0, b1_0, nullptr,
                                                        nullptr, nullptr, B1);
    // L1: B1 -> P1 (grid 16 x 16), u = 2t+kk
    k_conv<512, 11, 12, 5, 2, 1, 0, 3, 32, 16, 2, false, 0, 0>
        <<<dim3(16, 16), 256, 0, stream>>>(B1, w2_0, P1);
    // R1: H0 = relu(relu(sum P1 + b2_0) + sum PD + bd0)
    k_red<16, 5, 12, 8, false><<<512, 256, 0, stream>>>(P1, b2_0, PD, bd0,
                                                        nullptr, H0);
    // L2: H0 -> P2 (grid 16 x 16), u = t+kk
    k_conv<512, 5, 12, 3, 1, 1, 0, 3, 32, 16, 2, false, 0, 0>
        <<<dim3(16, 16), 256, 0, stream>>>(H0, w1_1, P2);
    // R2: B2 = relu(sum P2 + b1_1)
    k_red<16, 3, 4, 0, false><<<512, 256, 0, stream>>>(P2, b1_1, nullptr,
                                                       nullptr, nullptr, B2);
    // L3: B2 -> P3 (grid 16 x 8), u = kk
    k_conv<512, 3, 4, 1, 1, 1, 0, 3, 32, 32, 2, false, 0, 0>
        <<<dim3(16, 8), 256, 0, stream>>>(B2, w2_1, P3);
    // R3: H1 = relu(relu(sum P3 + b2_1) + H0[t=1023])
    k_red<8, 1, 1, 0, true><<<512, 256, 0, stream>>>(P3, b2_1, nullptr, nullptr,
                                                     H0, H1g);
    k_fc<<<OUTD, 64, 0, stream>>>(H1g, fcw, fcb, out);
}

// Round 9
// 117.654 us; speedup vs baseline: 2.7934x; 1.0621x over previous
//
#include <hip/hip_runtime.h>

// TCN, last-timestep receptive-field cone. PROVEN round-4 pipeline (passed,
// 125us), with the two independent kernels (L0 conv, downsample conv) merged
// into one launch via a block-role split. All math bodies are verbatim
// round-4 code; conv_body differs only by taking (bx,by) instead of reading
// blockIdx directly.
//
// Activations stored [c][b][TP]. Partials [ks][512][T][64].
// t maps: L0 u=ti+kk (x t=1011+u); down u=tj (x t=1015+2u);
// L1 u=2tj+kk (B1); L2 u=tk+kk (H0); L3 u=kk (B2).

#define OUTD 36

// ---- generic split-K conv-GEMM body (round-4 verbatim, bx/by params) ----
template <int CIN, int TS_N, int TP, int TOUT, int S, int D, int OFF, int TAPS,
          int OCT, int CCH, int NCH, bool SRC_X, int TS_BASE, int TS_STEP>
__device__ __forceinline__ void conv_body(int bx, int by,
                                          const float* __restrict__ src,
                                          const float* __restrict__ w,
                                          float* __restrict__ Pout) {
    const int tid = threadIdx.x, lane = tid & 63, wv = tid >> 6;
    const int oc0 = bx * OCT;
    constexpr int OCR = OCT / 4;
    __shared__ float Als[CCH * TAPS * OCT];
    __shared__ float Bls[CCH * 64 * TP];
    float acc[OCR][TOUT];
#pragma unroll
    for (int i = 0; i < OCR; ++i)
#pragma unroll
        for (int t = 0; t < TOUT; ++t) acc[i][t] = 0.f;

    for (int ch = 0; ch < NCH; ++ch) {
        const int c0 = (by * NCH + ch) * CCH;
        if (ch) __syncthreads();
        // stage weights: Als[c][kk][oc]
        for (int idx = tid; idx < OCT * CCH * TAPS; idx += 256) {
            int i = idx / (CCH * TAPS), r = idx % (CCH * TAPS);
            int c = r / TAPS, kk = r % TAPS;
            Als[(c * TAPS + kk) * OCT + i] =
                w[(size_t)(oc0 + i) * (CIN * TAPS) + (c0 + c) * TAPS + kk];
        }
        // stage activations: Bls[c][b][u]
        if constexpr (SRC_X) {
            for (int idx = tid; idx < CCH * TS_N * 64; idx += 256) {
                int c = idx % CCH, rb = idx / CCH;
                int b = rb & 63, u = rb >> 6;
                Bls[(c * 64 + b) * TP + u] =
                    src[((size_t)b * 1024 + 1011 + TS_BASE + TS_STEP * u) * 256 +
                        c0 + c];
            }
        } else {
            const float4* gp = (const float4*)(src + (size_t)c0 * 64 * TP);
            float4* lp = (float4*)Bls;
            for (int idx = tid; idx < CCH * 64 * TP / 4; idx += 256)
                lp[idx] = gp[idx];
        }
        __syncthreads();
        constexpr int NLOAD = (TP % 4 == 0) ? TP : TS_N;
        for (int c = 0; c < CCH; ++c) {
            float bv[NLOAD];
            if constexpr (TP % 4 == 0) {
#pragma unroll
                for (int q = 0; q < TP / 4; ++q)
                    *(float4*)&bv[4 * q] =
                        *(const float4*)&Bls[(c * 64 + lane) * TP + 4 * q];
            } else {
#pragma unroll
                for (int u = 0; u < TS_N; ++u)
                    bv[u] = Bls[(c * 64 + lane) * TP + u];
            }
            float av[TAPS][OCR];
#pragma unroll
            for (int kk = 0; kk < TAPS; ++kk)
#pragma unroll
                for (int j = 0; j < OCR; j += 4)
                    *(float4*)&av[kk][j] =
                        *(const float4*)&Als[(c * TAPS + kk) * OCT + wv * OCR + j];
#pragma unroll
            for (int i = 0; i < OCR; ++i)
#pragma unroll
                for (int t = 0; t < TOUT; ++t)
#pragma unroll
                    for (int kk = 0; kk < TAPS; ++kk)
                        acc[i][t] += av[kk][i] * bv[S * t + D * kk + OFF];
        }
    }
#pragma unroll
    for (int i = 0; i < OCR; ++i)
#pragma unroll
        for (int t = 0; t < TOUT; ++t)
            Pout[(((size_t)by * 512 + oc0 + wv * OCR + i) * TOUT + t) * 64 +
                 lane] = acc[i][t];
}

// standalone wrapper (round-4 k_conv semantics)
template <int CIN, int TS_N, int TP, int TOUT, int S, int D, int OFF, int TAPS,
          int OCT, int CCH, int NCH, bool SRC_X, int TS_BASE, int TS_STEP>
__global__ __launch_bounds__(256) void k_conv(const float* __restrict__ src,
                                              const float* __restrict__ w,
                                              float* __restrict__ Pout) {
    conv_body<CIN, TS_N, TP, TOUT, S, D, OFF, TAPS, OCT, CCH, NCH, SRC_X,
              TS_BASE, TS_STEP>(blockIdx.x, blockIdx.y, src, w, Pout);
}

// merged L0 (blocks 0..255: 32 ocp x 8 ks) + down (blocks 256..383: 16 x 8)
__global__ __launch_bounds__(256) void k_l0dn(const float* __restrict__ x,
                                              const float* __restrict__ w1_0,
                                              const float* __restrict__ wd0,
                                              float* __restrict__ P0,
                                              float* __restrict__ PD) {
    if (blockIdx.x < 256) {
        conv_body<256, 13, 13, 11, 1, 1, 0, 3, 16, 16, 2, true, 0, 1>(
            blockIdx.x >> 3, blockIdx.x & 7, x, w1_0, P0);
    } else {
        const int q = blockIdx.x - 256;
        conv_body<256, 5, 5, 5, 1, 0, 0, 1, 32, 16, 2, true, 4, 2>(
            q >> 3, q & 7, x, wd0, PD);
    }
}

// ---- reduce (round-4 verbatim): out[oc][b][TPo] -------------------------
template <int KS1, int T, int TPo, int KS2, bool RES>
__global__ __launch_bounds__(256) void k_red(const float* __restrict__ P1,
                                             const float* __restrict__ bias1,
                                             const float* __restrict__ P2,
                                             const float* __restrict__ bias2,
                                             const float* __restrict__ res,
                                             float* __restrict__ outp) {
    const int oc = blockIdx.x, tid = threadIdx.x;
    __shared__ float Sm[64 * TPo];
    if constexpr (TPo > 1) {
        for (int i = tid; i < 64 * TPo; i += 256) Sm[i] = 0.f;
        __syncthreads();
    }
    if (tid < T * 16) {
        const int t = tid / 16, b4 = (tid % 16) * 4;
        float4 s = make_float4(0.f, 0.f, 0.f, 0.f);
#pragma unroll
        for (int p = 0; p < KS1; ++p) {
            float4 u =
                *(const float4*)(P1 + (((size_t)p * 512 + oc) * T + t) * 64 + b4);
            s.x += u.x; s.y += u.y; s.z += u.z; s.w += u.w;
        }
        const float b1 = bias1[oc];
        s.x = fmaxf(s.x + b1, 0.f); s.y = fmaxf(s.y + b1, 0.f);
        s.z = fmaxf(s.z + b1, 0.f); s.w = fmaxf(s.w + b1, 0.f);
        if constexpr (KS2 > 0) {
            float4 s2 = make_float4(0.f, 0.f, 0.f, 0.f);
#pragma unroll
            for (int p = 0; p < KS2; ++p) {
                float4 u =
                    *(const float4*)(P2 + (((size_t)p * 512 + oc) * T + t) * 64 + b4);
                s2.x += u.x; s2.y += u.y; s2.z += u.z; s2.w += u.w;
            }
            const float b2v = bias2[oc];
            s.x = fmaxf(s.x + s2.x + b2v, 0.f);
            s.y = fmaxf(s.y + s2.y + b2v, 0.f);
            s.z = fmaxf(s.z + s2.z + b2v, 0.f);
            s.w = fmaxf(s.w + s2.w + b2v, 0.f);
        }
        if constexpr (RES) {
            s.x = fmaxf(s.x + res[((size_t)oc * 64 + b4 + 0) * 12 + 4], 0.f);
            s.y = fmaxf(s.y + res[((size_t)oc * 64 + b4 + 1) * 12 + 4], 0.f);
            s.z = fmaxf(s.z + res[((size_t)oc * 64 + b4 + 2) * 12 + 4], 0.f);
            s.w = fmaxf(s.w + res[((size_t)oc * 64 + b4 + 3) * 12 + 4], 0.f);
        }
        if constexpr (TPo == 1) {
            *(float4*)(outp + (size_t)oc * 64 + b4) = s;
        } else {
            Sm[(b4 + 0) * TPo + t] = s.x;
            Sm[(b4 + 1) * TPo + t] = s.y;
            Sm[(b4 + 2) * TPo + t] = s.z;
            Sm[(b4 + 3) * TPo + t] = s.w;
        }
    }
    if constexpr (TPo > 1) {
        __syncthreads();
        float4* op = (float4*)(outp + (size_t)oc * 64 * TPo);
        for (int i = tid; i < 64 * TPo / 4; i += 256)
            op[i] = *(const float4*)&Sm[4 * i];
    }
}

// ---- fc (round-4 verbatim) ----------------------------------------------
__global__ __launch_bounds__(64) void k_fc(const float* __restrict__ H1,
                                           const float* __restrict__ fcw,
                                           const float* __restrict__ fcb,
                                           float* __restrict__ out) {
    const int j = blockIdx.x, lane = threadIdx.x;
    float acc = fcb[j];
#pragma unroll 8
    for (int o = 0; o < 512; ++o) acc += fcw[j * 512 + o] * H1[o * 64 + lane];
    out[lane * OUTD + j] = acc;
}

extern "C" void kernel_launch(void* const* d_in, const int* in_sizes, int n_in,
                              void* d_out, int out_size, void* d_ws, size_t ws_size,
                              hipStream_t stream) {
    const float* x    = (const float*)d_in[0];
    const float* w1_0 = (const float*)d_in[4];
    const float* b1_0 = (const float*)d_in[5];
    const float* w2_0 = (const float*)d_in[6];
    const float* b2_0 = (const float*)d_in[7];
    const float* wd0  = (const float*)d_in[8];
    const float* bd0  = (const float*)d_in[9];
    const float* w1_1 = (const float*)d_in[10];
    const float* b1_1 = (const float*)d_in[11];
    const float* w2_1 = (const float*)d_in[12];
    const float* b2_1 = (const float*)d_in[13];
    const float* fcw  = (const float*)d_in[14];
    const float* fcb  = (const float*)d_in[15];
    float* out = (float*)d_out;

    // round-4 workspace layout, verbatim (38.4 MB, no aliasing)
    float* P0  = (float*)d_ws;                 // 8*512*11*64
    float* B1  = P0 + 8 * 512 * 11 * 64;       // 512*64*12
    float* P1  = B1 + 512 * 64 * 12;           // 16*512*5*64
    float* PD  = P1 + 16 * 512 * 5 * 64;       // 8*512*5*64
    float* H0  = PD + 8 * 512 * 5 * 64;        // 512*64*12
    float* P2  = H0 + 512 * 64 * 12;           // 16*512*3*64
    float* B2  = P2 + 16 * 512 * 3 * 64;       // 512*64*4
    float* P3  = B2 + 512 * 64 * 4;            // 8*512*64
    float* H1g = P3 + 8 * 512 * 64;            // 512*64

    // 1. L0 + down, merged (independent outputs)
    k_l0dn<<<384, 256, 0, stream>>>(x, w1_0, wd0, P0, PD);
    // 2. R0: B1 = relu(sum P0 + b1_0)
    k_red<8, 11, 12, 0, false><<<512, 256, 0, stream>>>(P0, b1_0, nullptr,
                                                        nullptr, nullptr, B1);
    // 3. L1: B1 -> P1 (u = 2t+kk)
    k_conv<512, 11, 12, 5, 2, 1, 0, 3, 32, 16, 2, false, 0, 0>
        <<<dim3(16, 16), 256, 0, stream>>>(B1, w2_0, P1);
    // 4. R1: H0 = relu(relu(sum P1 + b2_0) + sum PD + bd0)
    k_red<16, 5, 12, 8, false><<<512, 256, 0, stream>>>(P1, b2_0, PD, bd0,
                                                        nullptr, H0);
    // 5. L2: H0 -> P2 (u = t+kk)
    k_conv<512, 5, 12, 3, 1, 1, 0, 3, 32, 16, 2, false, 0, 0>
        <<<dim3(16, 16), 256, 0, stream>>>(H0, w1_1, P2);
    // 6. R2: B2 = relu(sum P2 + b1_1)
    k_red<16, 3, 4, 0, false><<<512, 256, 0, stream>>>(P2, b1_1, nullptr,
                                                       nullptr, nullptr, B2);
    // 7. L3: B2 -> P3 (u = kk)
    k_conv<512, 3, 4, 1, 1, 1, 0, 3, 32, 32, 2, false, 0, 0>
        <<<dim3(16, 8), 256, 0, stream>>>(B2, w2_1, P3);
    // 8. R3: H1 = relu(relu(sum P3 + b2_1) + H0[t=1023])
    k_red<8, 1, 1, 0, true><<<512, 256, 0, stream>>>(P3, b2_1, nullptr, nullptr,
                                                     H0, H1g);
    // 9. fc
    k_fc<<<OUTD, 64, 0, stream>>>(H1g, fcw, fcb, out);
}